// Round 2
// baseline (215.969 us; speedup 1.0000x reference)
//
#include <hip/hip_runtime.h>
#include <cstdint>
#include <cstddef>

// dec: [16, 3999, 512] fp32, wgt: [16, 512] fp32, out: [16, 32000] fp32
//   est[f][w] = dot(dec[f], wgt[w]);  out[8g+i] = est[g][i] + est[g-1][8+i]
//
// R8 structure: coalesced dec staging via global_load_lds (linear LDS dest,
// pre-swizzled global source, XOR-swizzled ds_read_b128 on the read side),
// double-buffered 16 KB chunks, one barrier per chunk. 4-way split is now
// over W (wave h owns output rows 4h..4h+3 over full K): 4 accumulators,
// wave-uniform weight addresses (scalarizable), no qq-reduction in epilogue.
//   R6/R7 post-mortem: weight-path swap (LDS broadcast vs scalar) was
//   neutral -> bottleneck is the x-stream's 64-distinct-lines-per-load
//   pattern (lane stride 2 KB). This version makes every global load
//   instruction move 1 KB of fully-used contiguous segments.

#define NBC     16
#define FRAMES  3999
#define EE      512
#define TOUT    32000
#define NGROUP  4000
#define GPB     63      // output groups per block (64 frame-slots)

__device__ __forceinline__ void gload_lds16(const float* src, float* dst) {
    __builtin_amdgcn_global_load_lds(
        (const __attribute__((address_space(1))) void*)src,
        (__attribute__((address_space(3))) void*)dst,
        16, 0, 0);
}

__global__ __launch_bounds__(256, 4) void decoder_kernel(
    const float* __restrict__ dec,
    const float* __restrict__ wgt,
    float* __restrict__ out)
{
    __shared__ __align__(16) float xbuf[2][64 * 64];  // 2 x 16 KB chunk tiles
    float* red = xbuf[0];                             // 4 KB overlay after loop

    const int tid   = threadIdx.x;
    const int bc    = blockIdx.x >> 6;   // 0..15
    const int chunk = blockIdx.x & 63;   // 0..63
    const int g0    = chunk * GPB;

    const int s    = tid & 63;                                  // frame slot
    const int lane = tid & 63;
    const int h    = __builtin_amdgcn_readfirstlane(tid >> 6);  // w-group (wave-uniform)

    const int f = g0 - 1 + s;
    const float vmask = (f >= 0 && f < FRAMES) ? 1.0f : 0.0f;

    const float* decb = dec + (size_t)bc * FRAMES * EE;

    // ---- staging plan: 1024 float4 units per chunk, 4 per thread ----
    // unit l = h*256 + i*64 + lane; frame slot = l>>4;
    // source f4 within frame's 64-float chunk = (l&15) ^ (frame&7)  (involution)
    // LDS dest byte = l*16 (linear, as global_load_lds requires)
    const float* srcp[4];
    float*       dstp[4];
    #pragma unroll
    for (int i = 0; i < 4; ++i) {
        const int l  = h * 256 + i * 64 + lane;
        const int fs = l >> 4;                        // frame slot 0..63
        const int us = (l & 15) ^ (fs & 7);           // pre-swizzled source f4
        const int ff = min(max(g0 - 1 + fs, 0), FRAMES - 1);
        srcp[i] = decb + (size_t)ff * EE + us * 4;    // + c*64 per chunk
        dstp[i] = &xbuf[0][0] + (size_t)l * 4;        // + 4096 for buffer 1
    }

    float acc[4] = {0.f, 0.f, 0.f, 0.f};
    const float* wb = wgt + (h * 4) * EE;             // this wave's 4 weight rows

    // ---- prologue: stage chunk 0 into buf 0 ----
    #pragma unroll
    for (int i = 0; i < 4; ++i)
        gload_lds16(srcp[i], dstp[i]);
    __syncthreads();                     // compiler drains vmcnt before barrier

    // ---- main loop: stage c+1 while computing c; one barrier per chunk ----
    #pragma unroll
    for (int c = 0; c < 8; ++c) {
        const int cur = c & 1;
        if (c < 7) {
            const int nxt = (c + 1) & 1;
            #pragma unroll
            for (int i = 0; i < 4; ++i)
                gload_lds16(srcp[i] + (c + 1) * 64, dstp[i] + nxt * 4096);
        }

        const float* xb = xbuf[cur];
        #pragma unroll
        for (int hf = 0; hf < 2; ++hf) {
            // lane s reads 8 float4 of its frame, XOR-swizzled -> conflict-free
            float4 xv[8];
            #pragma unroll
            for (int u8 = 0; u8 < 8; ++u8) {
                const int u = hf * 8 + u8;
                xv[u8] = *(const float4*)(xb + s * 64 + ((4 * u) ^ ((s & 7) << 2)));
            }
            #pragma unroll
            for (int w = 0; w < 4; ++w) {
                const float* wr = wb + w * EE + c * 64 + hf * 32;  // wave-uniform
                #pragma unroll
                for (int u8 = 0; u8 < 8; ++u8) {
                    acc[w] += xv[u8].x * wr[4 * u8 + 0]
                            + xv[u8].y * wr[4 * u8 + 1]
                            + xv[u8].z * wr[4 * u8 + 2]
                            + xv[u8].w * wr[4 * u8 + 3];
                }
            }
        }
        __syncthreads();   // vmcnt drain (next-chunk stage) + barrier
    }

    // ---- est[f][w] -> red[w][s] (full-K result, no q-reduction needed) ----
    #pragma unroll
    for (int w = 0; w < 4; ++w)
        red[(h * 4 + w) * 64 + s] = acc[w] * vmask;
    __syncthreads();

    // ---- fused overlap-add: 504 outputs, 256 threads -> 2 iterations ----
    for (int o = tid; o < GPB * 8; o += 256) {
        const int j = o >> 3;            // group offset in block, 0..62
        const int i = o & 7;             // sample within group
        const int g = g0 + j;
        if (g < NGROUP)
            out[(size_t)bc * TOUT + g * 8 + i]
                = red[i * 64 + (j + 1)]          // est[g][i]
                + red[(8 + i) * 64 + j];         // est[g-1][8+i]
    }
}

extern "C" void kernel_launch(void* const* d_in, const int* in_sizes, int n_in,
                              void* d_out, int out_size, void* d_ws, size_t ws_size,
                              hipStream_t stream) {
    const float* dec = (const float*)d_in[0];   // [8,2,3999,512] fp32
    const float* wgt = (const float*)d_in[1];   // [16,512] fp32
    float* out = (float*)d_out;                 // [8,2,32000] fp32

    decoder_kernel<<<dim3(1024), dim3(256), 0, stream>>>(dec, wgt, out);
}

// Round 4
// 196.539 us; speedup vs baseline: 1.0989x; 1.0989x over previous
//
#include <hip/hip_runtime.h>
#include <cstdint>
#include <cstddef>

// dec: [16, 3999, 512] fp32, wgt: [16, 512] fp32, out: [16, 32000] fp32
//   est[f][w] = dot(dec[f], wgt[w]);  out[8g+i] = est[g][i] + est[g-1][8+i]
//
// R10 = R9 resubmission (R9 hit an infra failure, never ran) with lower
// register pressure: rolling float4 xv[2][2] prefetch (32 B ahead) instead
// of xv[2][4], keeping peak VGPR well under the 64/lane cap that
// __launch_bounds__(512,8) imposes (8 waves/SIMD -> 32 waves/CU).
//
// Structure: direct (unstaged) frame-per-lane loads, ZERO main-loop
// barriers, 8-way K-split, weights via wave-uniform scalar loads, LDS =
// padded reduction buffer only (stride 65 kills epilogue bank conflicts).
//   R8 post-mortem: per-chunk __syncthreads (vmcnt(0) drain) lockstepped
//   all waves against HBM latency -> 81 us with every pipe idle. Staging
//   had zero reuse (each dec element consumed once) -> direct loads;
//   attack latency with occupancy + pipeline depth instead.

#define NBC     16
#define FRAMES  3999
#define EE      512
#define TOUT    32000
#define NGROUP  4000
#define GPB     63      // output groups per block (64 frame-slots)
#define RSTR    65      // red row stride (pad: 64+1)

__global__ __launch_bounds__(512, 8) void decoder_kernel(
    const float* __restrict__ dec,
    const float* __restrict__ wgt,
    float* __restrict__ out)
{
    __shared__ float red[8 * 16 * RSTR];   // ~33 KB reduction buffer

    const int tid   = threadIdx.x;
    const int bc    = blockIdx.x >> 6;   // 0..15
    const int chunk = blockIdx.x & 63;   // 0..63
    const int g0    = chunk * GPB;

    const int s = tid & 63;              // frame slot
    // K-eighth: wave-uniform; readfirstlane makes uniformity provable so
    // weight loads scalarize (s_load) instead of per-lane vector loads.
    const int q = __builtin_amdgcn_readfirstlane(tid >> 6);    // 0..7

    const int f = g0 - 1 + s;
    const float vmask = (f >= 0 && f < FRAMES) ? 1.0f : 0.0f;
    const int fr = min(max(f, 0), FRAMES - 1);   // clamped row for safe loads

    // this thread's contiguous 64-float (256 B) K-slice of its frame
    const float* arow = dec + ((size_t)bc * FRAMES + fr) * EE + q * 64;
    const float* wrow = wgt + q * 64;            // wave-uniform base

    float acc[16];
    #pragma unroll
    for (int w = 0; w < 16; ++w) acc[w] = 0.f;

    // 8 chunks of 8 floats (32 B half-lines); rolling 2-deep buffer so the
    // next half-line is in flight during this chunk's FMAs. No barriers.
    float4 xv[2][2];
    #pragma unroll
    for (int u = 0; u < 2; ++u)
        xv[0][u] = *(const float4*)(arow + 4 * u);

    #pragma unroll
    for (int c = 0; c < 8; ++c) {
        const int cur = c & 1;           // compile-time after unroll
        if (c < 7) {
            #pragma unroll
            for (int u = 0; u < 2; ++u)
                xv[cur ^ 1][u] = *(const float4*)(arow + (c + 1) * 8 + 4 * u);
        }
        #pragma unroll
        for (int w = 0; w < 16; ++w) {
            // uniform address -> s_load; FMA reads the SGPR operand (free bcast)
            const float* wr = wrow + w * EE + c * 8;
            float sum = acc[w];
            #pragma unroll
            for (int u = 0; u < 2; ++u) {
                sum += xv[cur][u].x * wr[4 * u + 0];
                sum += xv[cur][u].y * wr[4 * u + 1];
                sum += xv[cur][u].z * wr[4 * u + 2];
                sum += xv[cur][u].w * wr[4 * u + 3];
            }
            acc[w] = sum;
        }
    }

    // ---- 8-way K-split partials -> LDS ----
    #pragma unroll
    for (int w = 0; w < 16; ++w)
        red[(q * 16 + w) * RSTR + s] = acc[w] * vmask;
    __syncthreads();

    // ---- fused overlap-add: 504 outputs, 512 threads -> 1 iteration ----
    if (tid < GPB * 8) {
        const int j = tid >> 3;          // group offset in block, 0..62
        const int i = tid & 7;           // sample within group
        const int g = g0 + j;
        if (g < NGROUP) {
            float v = 0.f;
            #pragma unroll
            for (int qq = 0; qq < 8; ++qq)
                v += red[(qq * 16 + i) * RSTR + (j + 1)]     // est[g][i]
                   + red[(qq * 16 + 8 + i) * RSTR + j];      // est[g-1][8+i]
            out[(size_t)bc * TOUT + g * 8 + i] = v;
        }
    }
}

extern "C" void kernel_launch(void* const* d_in, const int* in_sizes, int n_in,
                              void* d_out, int out_size, void* d_ws, size_t ws_size,
                              hipStream_t stream) {
    const float* dec = (const float*)d_in[0];   // [8,2,3999,512] fp32
    const float* wgt = (const float*)d_in[1];   // [16,512] fp32
    float* out = (float*)d_out;                 // [8,2,32000] fp32

    decoder_kernel<<<dim3(1024), dim3(512), 0, stream>>>(dec, wgt, out);
}